// Round 3
// baseline (446.222 us; speedup 1.0000x reference)
//
#include <hip/hip_runtime.h>

// Fused ReconstructionHead: h = x[:, :-1] @ W1^T + b1; LayerNorm*gamma+beta;
// relu; out[b,t] = dot(h, Wout[t]) + bout[t].  M = 131072 rows, K = N = 512.
//
// R3 vs R2 (176.7 us kernel, MfmaUtil 16%, everything idle):
//  - double-buffered LDS (A and B), ONE barrier per chunk: B-DMA for chunk
//    c+1 issued at top of chunk c, drained by the barrier AFTER chunk c's
//    MFMAs -> staging overlaps compute instead of serializing.
//  - MT=128, 1024 threads (16 waves, 32x128 tile each): W1 L2 re-fetch
//    halved (512 MB), 2x MFMA per chunk per DMA byte. Grid = 1024 = 4 clean
//    rounds of 256 CUs, 1 block/CU (LDS 91 KB).
//  - B k-group XOR swizzle: lane fetches k-group (i&3)^(row&3) -> same global
//    addresses (coalescing intact), swizzled LDS placement -> 8-way bank
//    conflict on fragment ds_read_b128 drops to 4-way.

#define DIN     512
#define BK      32
#define MT      128           // rows per block
#define THREADS 1024          // 16 waves
#define NCHUNK  (DIN / BK)    // 16
#define ASTR    40            // A row stride in shorts (32 + 8 pad)
#define BROW    32            // B row stride in shorts (64 B, DMA-contiguous)

typedef __attribute__((ext_vector_type(8))) short bf16x8;
typedef __attribute__((ext_vector_type(4))) float f32x4;

__device__ __forceinline__ short f2bf(float f) {
    unsigned u = __float_as_uint(f);
    u = u + 0x7fffu + ((u >> 16) & 1u);   // RNE
    return (short)(u >> 16);
}

__device__ __forceinline__ void gload_lds16(const void* g, void* l) {
    __builtin_amdgcn_global_load_lds(
        (const __attribute__((address_space(1))) unsigned int*)g,
        (__attribute__((address_space(3))) unsigned int*)l,
        16, 0, 0);
}

__global__ void cvt_w1_kernel(const float* __restrict__ w, short* __restrict__ o) {
    int i = blockIdx.x * blockDim.x + threadIdx.x;   // 65536 threads, 4 elems each
    float4 v = ((const float4*)w)[i];
    short4 s;
    s.x = f2bf(v.x); s.y = f2bf(v.y); s.z = f2bf(v.z); s.w = f2bf(v.w);
    ((short4*)o)[i] = s;
}

// fallback staging: fp32 W1 -> bf16 LDS with the same XOR-swizzled layout
__device__ __forceinline__ void stage_b_f32(short* bsb, const float* W1f,
                                            int c, int tid) {
    if (tid < DIN) {
        const float* src = W1f + (size_t)tid * DIN + c * BK;
        const int rp = tid & 3;
#pragma unroll
        for (int g = 0; g < 4; ++g) {
            float4 v0 = *(const float4*)(src + g * 8);
            float4 v1 = *(const float4*)(src + g * 8 + 4);
            bf16x8 s;
            s[0] = f2bf(v0.x); s[1] = f2bf(v0.y); s[2] = f2bf(v0.z); s[3] = f2bf(v0.w);
            s[4] = f2bf(v1.x); s[5] = f2bf(v1.y); s[6] = f2bf(v1.z); s[7] = f2bf(v1.w);
            *(bf16x8*)(bsb + tid * BROW + ((g ^ rp) * 8)) = s;
        }
    }
}

template<bool WS>
__global__ __launch_bounds__(THREADS)
void fused_head_kernel(const float* __restrict__ x,
                       const float* __restrict__ W1f,
                       const short* __restrict__ W1h,
                       const float* __restrict__ b1,
                       const float* __restrict__ gamma,
                       const float* __restrict__ beta,
                       const float* __restrict__ Wout,
                       const float* __restrict__ bout,
                       float* __restrict__ out) {
    __shared__ __align__(16) short As[2][MT * ASTR];    // 20480 B
    __shared__ __align__(16) short Bs[2][DIN * BROW];   // 65536 B
    __shared__ float redS[MT][4];
    __shared__ float redQ[MT][4];
    __shared__ float meanA[MT];
    __shared__ float rstdA[MT];

    const int tid  = threadIdx.x;
    const int w    = tid >> 6;        // wave 0..15
    const int lane = tid & 63;
    const int q    = lane >> 4;       // quad 0..3
    const int l15  = lane & 15;
    const int rg   = w >> 2;          // row group 0..3 (32 rows each)
    const int cg   = w & 3;           // col group 0..3 (128 cols each)

    const int m0 = blockIdx.x * MT;
    const int bb = m0 >> 9;           // batch index
    const int t0 = m0 & 511;          // first t (multiple of 128)
    const float* xbase = x + (size_t)(bb * 513 + t0) * DIN;

    // A staging: 1024 threads cover 128 rows x 32 k fp32 (one float4 each)
    const int ar = tid >> 3;          // row 0..127
    const int ak = (tid & 7) * 4;     // k offset (floats)

    // B DMA: wave w stages rows [w*32, w*32+32) as two 1KB instrs (16 rows).
    // lane i: row = base + (i>>2); fetches k-group (i&3)^(row&3) -> XOR layout.
    const int r16 = lane >> 2;
    const int kg  = (lane & 3) ^ (r16 & 3);
    const short* bG = W1h + (size_t)(w * 32 + r16) * DIN + kg * 8;

    f32x4 acc[2][8];
#pragma unroll
    for (int i = 0; i < 2; ++i)
#pragma unroll
        for (int j = 0; j < 8; ++j)
            acc[i][j] = (f32x4){0.f, 0.f, 0.f, 0.f};

    // ---- prologue: stage chunk 0 into buffer 0, prefetch chunk 1 ----
    float4 aReg = *(const float4*)(xbase + ar * DIN + ak);
    if (WS) {
        gload_lds16(bG,            &Bs[0][(w * 32) * BROW]);
        gload_lds16(bG + 16 * DIN, &Bs[0][(w * 32 + 16) * BROW]);
    } else {
        stage_b_f32(&Bs[0][0], W1f, 0, tid);
    }
    {
        short4 a4;
        a4.x = f2bf(aReg.x); a4.y = f2bf(aReg.y);
        a4.z = f2bf(aReg.z); a4.w = f2bf(aReg.w);
        *(short4*)(&As[0][ar * ASTR + ak]) = a4;
    }
    aReg = *(const float4*)(xbase + ar * DIN + BK + ak);   // chunk 1

    for (int c = 0; c < NCHUNK; ++c) {
        const int cur = c & 1, nxt = cur ^ 1;
        __syncthreads();   // drains: DMA+A-writes for chunk c; readers of buf nxt done
        if (c + 1 < NCHUNK) {
            if (WS) {
                const short* g = bG + (size_t)(c + 1) * BK;
                gload_lds16(g,            &Bs[nxt][(w * 32) * BROW]);
                gload_lds16(g + 16 * DIN, &Bs[nxt][(w * 32 + 16) * BROW]);
            } else {
                stage_b_f32(&Bs[nxt][0], W1f, c + 1, tid);
            }
            short4 a4;
            a4.x = f2bf(aReg.x); a4.y = f2bf(aReg.y);
            a4.z = f2bf(aReg.z); a4.w = f2bf(aReg.w);
            *(short4*)(&As[nxt][ar * ASTR + ak]) = a4;
            if (c + 2 < NCHUNK)
                aReg = *(const float4*)(xbase + ar * DIN + (c + 2) * BK + ak);
        }
        // ---- compute chunk c from buffer cur (overlaps in-flight DMA) ----
        bf16x8 af[2];
        const short* Ap = &As[cur][(rg * 32 + l15) * ASTR + q * 8];
        af[0] = *(const bf16x8*)Ap;
        af[1] = *(const bf16x8*)(Ap + 16 * ASTR);
        const short* Bp = &Bs[cur][(cg * 128 + l15) * BROW + ((q ^ (l15 & 3)) * 8)];
#pragma unroll
        for (int tj = 0; tj < 8; ++tj) {
            bf16x8 bf = *(const bf16x8*)(Bp + tj * 16 * BROW);
            acc[0][tj] = __builtin_amdgcn_mfma_f32_16x16x32_bf16(af[0], bf, acc[0][tj], 0, 0, 0);
            acc[1][tj] = __builtin_amdgcn_mfma_f32_16x16x32_bf16(af[1], bf, acc[1][tj], 0, 0, 0);
        }
    }

    // ================= epilogue =================
    float b1v[8], gv[8], bv[8];
    const int cb = cg * 128 + l15;
#pragma unroll
    for (int tj = 0; tj < 8; ++tj) {
        int col = cb + tj * 16;
        b1v[tj] = b1[col];
        gv[tj]  = gamma[col];
        bv[tj]  = beta[col];
    }

    // pass 1: row sums / sumsq.  C layout: col = l15, row = rg*32 + ti*16 + q*4 + r
#pragma unroll
    for (int ti = 0; ti < 2; ++ti)
#pragma unroll
        for (int r = 0; r < 4; ++r) {
            int row = rg * 32 + ti * 16 + q * 4 + r;
            float s = 0.f, s2 = 0.f;
#pragma unroll
            for (int tj = 0; tj < 8; ++tj) {
                float v = acc[ti][tj][r] + b1v[tj];
                s += v; s2 += v * v;
            }
#pragma unroll
            for (int m = 1; m < 16; m <<= 1) {
                s  += __shfl_xor(s,  m, 64);
                s2 += __shfl_xor(s2, m, 64);
            }
            if (l15 == 0) { redS[row][cg] = s; redQ[row][cg] = s2; }
        }
    __syncthreads();
    if (tid < MT) {
        float s  = redS[tid][0] + redS[tid][1] + redS[tid][2] + redS[tid][3];
        float s2 = redQ[tid][0] + redQ[tid][1] + redQ[tid][2] + redQ[tid][3];
        float mean = s * (1.f / DIN);
        float var  = s2 * (1.f / DIN) - mean * mean;
        meanA[tid] = mean;
        rstdA[tid] = rsqrtf(fmaxf(var, 0.f) + 1e-5f);
    }
    __syncthreads();

    // pass 2: normalize + relu + dot with Wout[t]
#pragma unroll
    for (int ti = 0; ti < 2; ++ti)
#pragma unroll
        for (int r = 0; r < 4; ++r) {
            int row = rg * 32 + ti * 16 + q * 4 + r;
            float mean = meanA[row], rs = rstdA[row];
            const float* wrow = Wout + (size_t)(t0 + row) * DIN + cb;
            float s = 0.f;
#pragma unroll
            for (int tj = 0; tj < 8; ++tj) {
                float v = acc[ti][tj][r] + b1v[tj];
                v = (v - mean) * rs * gv[tj] + bv[tj];
                v = fmaxf(v, 0.f);
                s += v * wrow[tj * 16];
            }
#pragma unroll
            for (int m = 1; m < 16; m <<= 1)
                s += __shfl_xor(s, m, 64);
            if (l15 == 0) redS[row][cg] = s;
        }
    __syncthreads();
    if (tid < MT)
        out[m0 + tid] = redS[tid][0] + redS[tid][1] + redS[tid][2] + redS[tid][3]
                        + bout[t0 + tid];
}

extern "C" void kernel_launch(void* const* d_in, const int* in_sizes, int n_in,
                              void* d_out, int out_size, void* d_ws, size_t ws_size,
                              hipStream_t stream) {
    const float* x     = (const float*)d_in[0];
    const float* W1    = (const float*)d_in[1];
    const float* b1    = (const float*)d_in[2];
    const float* gamma = (const float*)d_in[3];
    const float* beta  = (const float*)d_in[4];
    const float* Wout  = (const float*)d_in[5];
    const float* bout  = (const float*)d_in[6];
    float* out = (float*)d_out;

    const int M = 256 * 512;
    dim3 grid(M / MT), block(THREADS);

    if (ws_size >= (size_t)(DIN * DIN) * sizeof(short)) {
        short* W1h = (short*)d_ws;
        cvt_w1_kernel<<<DIN * DIN / (256 * 4), 256, 0, stream>>>(W1, W1h);
        fused_head_kernel<true><<<grid, block, 0, stream>>>(
            x, W1, W1h, b1, gamma, beta, Wout, bout, out);
    } else {
        fused_head_kernel<false><<<grid, block, 0, stream>>>(
            x, W1, nullptr, b1, gamma, beta, Wout, bout, out);
    }
}